// Round 1
// baseline (2333.214 us; speedup 1.0000x reference)
//
#include <hip/hip_runtime.h>
#include <hip/hip_bf16.h>

#define N_NODES 100000
#define N_EDGES 1600000
#define F_IN 128
#define N_GRAPHS 1000

// ---------------------------------------------------------------- utilities

__global__ __launch_bounds__(256) void init_deg_kernel(float* deg, int n) {
    int i = blockIdx.x * 256 + threadIdx.x;
    if (i < n) deg[i] = 1.0f;  // self-loop weight
}

__global__ __launch_bounds__(256) void deg_accum_kernel(const int* __restrict__ dst,
                                                        const float* __restrict__ ew,
                                                        float* deg, int e) {
    int i = blockIdx.x * 256 + threadIdx.x;
    if (i < e) atomicAdd(&deg[dst[i]], ew[i]);
}

__global__ __launch_bounds__(256) void dinv_kernel(float* deg, int n) {
    int i = blockIdx.x * 256 + threadIdx.x;
    if (i < n) {
        float d = deg[i];
        deg[i] = d > 0.f ? rsqrtf(fmaxf(d, 1e-12f)) : 0.f;
    }
}

__global__ __launch_bounds__(256) void zero_kernel(float* p, int n) {
    int i = blockIdx.x * 256 + threadIdx.x;
    if (i < n) p[i] = 0.f;
}

// ---------------------------------------------------------------- GEMM + dinv scale
// out' = dinv[row] * (X[row,:] @ W)   written to BOTH outM and outAgg (agg init = self contribution)
// Block: 256 threads = 16x16, 64 rows per block, K-phased in chunks of 64.
template <int K, int NOUT>
__global__ __launch_bounds__(256) void gemm_scale_kernel(
    const float* __restrict__ X, const float* __restrict__ W,
    const float* __restrict__ dinv, float* __restrict__ outM,
    float* __restrict__ outAgg, int N) {
    constexpr int ROWS = 64;
    constexpr int KB = 64;
    constexpr int LDR = ROWS + 4;   // 68: pad keeps banks spread, 16B-aligned rows
    constexpr int CM = NOUT / 16;   // 4 (NOUT=64) or 2 (NOUT=32)

    __shared__ float Xt[KB * LDR];   // transposed: [k][row]
    __shared__ float Ws[KB * NOUT];  // [k][col]

    const int tid = threadIdx.x;
    const int tc = tid & 15;   // col group
    const int tr = tid >> 4;   // row group (0..15), 4 rows each
    const int rowBase = blockIdx.x * ROWS;

    float acc[4][CM];
#pragma unroll
    for (int i = 0; i < 4; ++i)
#pragma unroll
        for (int j = 0; j < CM; ++j) acc[i][j] = 0.f;

    for (int kb = 0; kb < K; kb += KB) {
        // stage X^T (64 rows x 64 k) — coalesced global read, transposed LDS write
#pragma unroll
        for (int it = 0; it < (ROWS * KB) / (256 * 4); ++it) {
            int flat = it * 1024 + tid * 4;
            int r = flat >> 6;   // row in tile
            int c = flat & 63;   // k in tile
            int grow = rowBase + r;
            float4 v = make_float4(0.f, 0.f, 0.f, 0.f);
            if (grow < N) v = *(const float4*)(X + (size_t)grow * K + kb + c);
            Xt[(c + 0) * LDR + r] = v.x;
            Xt[(c + 1) * LDR + r] = v.y;
            Xt[(c + 2) * LDR + r] = v.z;
            Xt[(c + 3) * LDR + r] = v.w;
        }
        // stage W (64 k x NOUT)
#pragma unroll
        for (int it = 0; it < (KB * NOUT) / (256 * 4); ++it) {
            int flat = it * 1024 + tid * 4;
            *(float4*)(Ws + flat) = *(const float4*)(W + kb * NOUT + flat);
        }
        __syncthreads();

#pragma unroll
        for (int k = 0; k < KB; ++k) {
            float4 xv = *(const float4*)(Xt + k * LDR + tr * 4);
            float xs[4] = {xv.x, xv.y, xv.z, xv.w};
            const float* wp = Ws + k * NOUT + tc * CM;
            float wv[CM];
#pragma unroll
            for (int j = 0; j < CM; ++j) wv[j] = wp[j];
#pragma unroll
            for (int i = 0; i < 4; ++i)
#pragma unroll
                for (int j = 0; j < CM; ++j) acc[i][j] = fmaf(xs[i], wv[j], acc[i][j]);
        }
        __syncthreads();
    }

#pragma unroll
    for (int i = 0; i < 4; ++i) {
        int r = rowBase + tr * 4 + i;
        if (r < N) {
            float d = dinv[r];
            float* pm = outM + (size_t)r * NOUT + tc * CM;
            float* pa = outAgg + (size_t)r * NOUT + tc * CM;
#pragma unroll
            for (int j = 0; j < CM; ++j) {
                float v = acc[i][j] * d;
                pm[j] = v;
                pa[j] = v;
            }
        }
    }
}

// ---------------------------------------------------------------- edge scatter (push, atomics)
// agg[dst] += w[e] * m'[src];  NOUT/4 lanes per edge, float4 gather + 4 f32 atomics
template <int NOUT>
__global__ __launch_bounds__(256) void scatter_kernel(
    const int* __restrict__ src, const int* __restrict__ dst,
    const float* __restrict__ ew, const float* __restrict__ mprime,
    float* __restrict__ agg, int E) {
    constexpr int SH = (NOUT == 64) ? 4 : 3;  // log2(NOUT/4)
    int gtid = blockIdx.x * 256 + threadIdx.x;
    int e = gtid >> SH;
    int c = gtid & ((1 << SH) - 1);
    if (e >= E) return;
    int s = src[e];
    int d = dst[e];
    float w = ew[e];
    float4 v = *(const float4*)(mprime + (size_t)s * NOUT + c * 4);
    float* ap = agg + (size_t)d * NOUT + c * 4;
    atomicAdd(ap + 0, v.x * w);
    atomicAdd(ap + 1, v.y * w);
    atomicAdd(ap + 2, v.z * w);
    atomicAdd(ap + 3, v.w * w);
}

// ---------------------------------------------------------------- finalize: h = relu(dinv*agg + b)
template <int NOUT>
__global__ __launch_bounds__(256) void finalize_kernel(
    const float* __restrict__ agg, const float* __restrict__ dinv,
    const float* __restrict__ bias, float* __restrict__ h, int N) {
    constexpr int CPE = NOUT / 4;
    int idx = blockIdx.x * 256 + threadIdx.x;
    if (idx >= N * CPE) return;
    int node = idx / CPE;
    int c = idx % CPE;
    float d = dinv[node];
    float4 v = *(const float4*)(agg + (size_t)node * NOUT + c * 4);
    float4 b = *(const float4*)(bias + c * 4);
    float4 o;
    o.x = fmaxf(fmaf(d, v.x, b.x), 0.f);
    o.y = fmaxf(fmaf(d, v.y, b.y), 0.f);
    o.z = fmaxf(fmaf(d, v.z, b.z), 0.f);
    o.w = fmaxf(fmaf(d, v.w, b.w), 0.f);
    *(float4*)(h + (size_t)node * NOUT + c * 4) = o;
}

// ---------------------------------------------------------------- fused finalize(layer2) + sum-pool
__global__ __launch_bounds__(256) void pool_kernel(
    const float* __restrict__ agg2, const float* __restrict__ dinv,
    const float* __restrict__ b1, const int* __restrict__ ngi,
    float* __restrict__ g, int N) {
    int idx = blockIdx.x * 256 + threadIdx.x;  // N * 8
    if (idx >= N * 8) return;
    int node = idx >> 3;
    int c = idx & 7;
    float d = dinv[node];
    float4 v = *(const float4*)(agg2 + (size_t)node * 32 + c * 4);
    float4 b = *(const float4*)(b1 + c * 4);
    int gi = ngi[node];
    float* gp = g + gi * 32 + c * 4;
    atomicAdd(gp + 0, fmaxf(fmaf(d, v.x, b.x), 0.f));
    atomicAdd(gp + 1, fmaxf(fmaf(d, v.y, b.y), 0.f));
    atomicAdd(gp + 2, fmaxf(fmaf(d, v.z, b.z), 0.f));
    atomicAdd(gp + 3, fmaxf(fmaf(d, v.w, b.w), 0.f));
}

// ---------------------------------------------------------------- MLP head: relu(g@Wm1+bm1) @ Wm2 + bm2
__global__ __launch_bounds__(128) void mlp_kernel(
    const float* __restrict__ g, const float* __restrict__ Wm1,
    const float* __restrict__ bm1, const float* __restrict__ Wm2,
    const float* __restrict__ bm2, float* __restrict__ out) {
    __shared__ float sg[32];
    __shared__ float st[128];
    int b = blockIdx.x, t = threadIdx.x;
    if (t < 32) sg[t] = g[b * 32 + t];
    __syncthreads();
    float acc = bm1[t];
#pragma unroll
    for (int k = 0; k < 32; ++k) acc = fmaf(sg[k], Wm1[k * 128 + t], acc);
    st[t] = fmaxf(acc, 0.f);
    __syncthreads();
    if (t < 2) {
        float o = bm2[t];
#pragma unroll
        for (int k = 0; k < 128; ++k) o = fmaf(st[k], Wm2[k * 2 + t], o);
        out[b * 2 + t] = o;
    }
}

// ---------------------------------------------------------------- launch

extern "C" void kernel_launch(void* const* d_in, const int* in_sizes, int n_in,
                              void* d_out, int out_size, void* d_ws, size_t ws_size,
                              hipStream_t stream) {
    const float* x   = (const float*)d_in[0];
    const int*   ei  = (const int*)d_in[1];
    const float* ew  = (const float*)d_in[2];
    const int*   ngi = (const int*)d_in[3];
    const float* W0  = (const float*)d_in[4];
    const float* b0  = (const float*)d_in[5];
    const float* W1  = (const float*)d_in[6];
    const float* b1  = (const float*)d_in[7];
    const float* Wm1 = (const float*)d_in[8];
    const float* bm1 = (const float*)d_in[9];
    const float* Wm2 = (const float*)d_in[10];
    const float* bm2 = (const float*)d_in[11];
    float* out = (float*)d_out;

    const int N = in_sizes[0] / F_IN;       // 100000
    const int E = in_sizes[1] / 2;          // 1600000
    const int G = out_size / 2;             // 1000
    const int* srcp = ei;
    const int* dstp = ei + E;

    // workspace layout (bytes): dinv | A(25.6MB) | B(25.6MB) | g
    char* wsb = (char*)d_ws;
    float* dinv = (float*)wsb;                         // N floats
    size_t off = ((size_t)N * 4 + 255) & ~(size_t)255; // 400128
    float* A = (float*)(wsb + off);                    // N*64 floats
    off += (size_t)N * 64 * 4;
    float* B = (float*)(wsb + off);                    // N*64 floats
    off += (size_t)N * 64 * 4;
    float* Gbuf = (float*)(wsb + off);                 // G*32 floats
    float* Blo = B;                                    // m1' (N*32)
    float* Bhi = B + (size_t)N * 32;                   // agg2 (N*32)

    // 1. degree + dinv (dinv buffer reused in place)
    init_deg_kernel<<<(N + 255) / 256, 256, 0, stream>>>(dinv, N);
    deg_accum_kernel<<<(E + 255) / 256, 256, 0, stream>>>(dstp, ew, dinv, E);
    dinv_kernel<<<(N + 255) / 256, 256, 0, stream>>>(dinv, N);

    // 2. layer 1: m0' = dinv*(x@W0) -> A, agg1 init -> B
    gemm_scale_kernel<128, 64><<<(N + 63) / 64, 256, 0, stream>>>(x, W0, dinv, A, B, N);
    scatter_kernel<64><<<(E * 16 + 255) / 256, 256, 0, stream>>>(srcp, dstp, ew, A, B, E);
    finalize_kernel<64><<<(N * 16 + 255) / 256, 256, 0, stream>>>(B, dinv, b0, A, N);

    // 3. layer 2: m1' = dinv*(h1@W1) -> Blo, agg2 init -> Bhi
    gemm_scale_kernel<64, 32><<<(N + 63) / 64, 256, 0, stream>>>(A, W1, dinv, Blo, Bhi, N);
    scatter_kernel<32><<<(E * 8 + 255) / 256, 256, 0, stream>>>(srcp, dstp, ew, Blo, Bhi, E);

    // 4. pool (fused finalize) + MLP head
    zero_kernel<<<(G * 32 + 255) / 256, 256, 0, stream>>>(Gbuf, G * 32);
    pool_kernel<<<(N * 8 + 255) / 256, 256, 0, stream>>>(Bhi, dinv, b1, ngi, Gbuf, N);
    mlp_kernel<<<G, 128, 0, stream>>>(Gbuf, Wm1, bm1, Wm2, bm2, out);
}

// Round 2
// 490.729 us; speedup vs baseline: 4.7546x; 4.7546x over previous
//
#include <hip/hip_runtime.h>
#include <hip/hip_bf16.h>

#define F_IN 128

// ---------------------------------------------------------------- small utils

__global__ __launch_bounds__(256) void zero_i_kernel(int* p, int n) {
    int i = blockIdx.x * 256 + threadIdx.x;
    if (i < n) p[i] = 0;
}

__global__ __launch_bounds__(256) void zero_f_kernel(float* p, int n) {
    int i = blockIdx.x * 256 + threadIdx.x;
    if (i < n) p[i] = 0.f;
}

// ---------------------------------------------------------------- CSR build (counting sort by dst)

__global__ __launch_bounds__(256) void count_kernel(const int* __restrict__ dst,
                                                    int* __restrict__ cnt, int e) {
    int i = blockIdx.x * 256 + threadIdx.x;
    if (i < e) atomicAdd(&cnt[dst[i]], 1);
}

// block-local exclusive scan; rowptr[i] = excl within block, part[b] = block total
__global__ __launch_bounds__(256) void scan_block_kernel(const int* __restrict__ cnt,
                                                         int* __restrict__ rowptr,
                                                         int* __restrict__ part, int n) {
    __shared__ int tmp[256];
    int i = blockIdx.x * 256 + threadIdx.x;
    int v = (i < n) ? cnt[i] : 0;
    tmp[threadIdx.x] = v;
    __syncthreads();
    for (int o = 1; o < 256; o <<= 1) {
        int t = (threadIdx.x >= o) ? tmp[threadIdx.x - o] : 0;
        __syncthreads();
        tmp[threadIdx.x] += t;
        __syncthreads();
    }
    if (i < n) rowptr[i] = tmp[threadIdx.x] - v;  // exclusive
    if (threadIdx.x == 255) part[blockIdx.x] = tmp[255];
}

// single-block scan of block partials (nb <= 512); part -> exclusive, part[nb] = total
__global__ __launch_bounds__(512) void scan_part_kernel(int* part, int nb) {
    __shared__ int tmp[512];
    int i = threadIdx.x;
    int v = (i < nb) ? part[i] : 0;
    tmp[i] = v;
    __syncthreads();
    for (int o = 1; o < 512; o <<= 1) {
        int t = (i >= o) ? tmp[i - o] : 0;
        __syncthreads();
        tmp[i] += t;
        __syncthreads();
    }
    if (i < nb) part[i] = tmp[i] - v;
    if (i == 0) part[nb] = tmp[nb - 1];
}

// rowptr[i] += part[blk]; cursor[i] = rowptr[i]; rowptr[n] = total
__global__ __launch_bounds__(256) void scan_add_kernel(int* __restrict__ rowptr,
                                                       int* __restrict__ cursor,
                                                       const int* __restrict__ part,
                                                       int n, int nb) {
    int i = blockIdx.x * 256 + threadIdx.x;
    if (i < n) {
        int v = rowptr[i] + part[blockIdx.x];
        rowptr[i] = v;
        cursor[i] = v;
    }
    if (i == n) rowptr[n] = part[nb];
}

// es[p] = {src, bits(w)} at p = cursor[dst]++
__global__ __launch_bounds__(256) void place_kernel(const int* __restrict__ src,
                                                    const int* __restrict__ dst,
                                                    const float* __restrict__ ew,
                                                    int* __restrict__ cursor,
                                                    int2* __restrict__ es, int e) {
    int i = blockIdx.x * 256 + threadIdx.x;
    if (i >= e) return;
    int d = dst[i];
    int p = atomicAdd(&cursor[d], 1);
    es[p] = make_int2(src[i], __float_as_int(ew[i]));
}

// dinv[i] = rsqrt(1 + sum of incoming w)   (deg >= 1 always, self-loop)
__global__ __launch_bounds__(256) void dinv_kernel(const int* __restrict__ rowptr,
                                                   const int2* __restrict__ es,
                                                   float* __restrict__ dinv, int n) {
    int i = blockIdx.x * 256 + threadIdx.x;
    if (i >= n) return;
    int b = rowptr[i], e = rowptr[i + 1];
    float s = 1.f;
    for (int p = b; p < e; ++p) s += __int_as_float(es[p].y);
    dinv[i] = rsqrtf(fmaxf(s, 1e-12f));
}

// ---------------------------------------------------------------- GEMM + dinv scale
// outM[row] = dinv[row] * (X[row,:] @ W)
template <int K, int NOUT>
__global__ __launch_bounds__(256) void gemm_scale_kernel(
    const float* __restrict__ X, const float* __restrict__ W,
    const float* __restrict__ dinv, float* __restrict__ outM, int N) {
    constexpr int ROWS = 64;
    constexpr int KB = 64;
    constexpr int LDR = ROWS + 4;
    constexpr int CM = NOUT / 16;

    __shared__ float Xt[KB * LDR];   // transposed: [k][row]
    __shared__ float Ws[KB * NOUT];  // [k][col]

    const int tid = threadIdx.x;
    const int tc = tid & 15;
    const int tr = tid >> 4;
    const int rowBase = blockIdx.x * ROWS;

    float acc[4][CM];
#pragma unroll
    for (int i = 0; i < 4; ++i)
#pragma unroll
        for (int j = 0; j < CM; ++j) acc[i][j] = 0.f;

    for (int kb = 0; kb < K; kb += KB) {
#pragma unroll
        for (int it = 0; it < (ROWS * KB) / (256 * 4); ++it) {
            int flat = it * 1024 + tid * 4;
            int r = flat >> 6;
            int c = flat & 63;
            int grow = rowBase + r;
            float4 v = make_float4(0.f, 0.f, 0.f, 0.f);
            if (grow < N) v = *(const float4*)(X + (size_t)grow * K + kb + c);
            Xt[(c + 0) * LDR + r] = v.x;
            Xt[(c + 1) * LDR + r] = v.y;
            Xt[(c + 2) * LDR + r] = v.z;
            Xt[(c + 3) * LDR + r] = v.w;
        }
#pragma unroll
        for (int it = 0; it < (KB * NOUT) / (256 * 4); ++it) {
            int flat = it * 1024 + tid * 4;
            *(float4*)(Ws + flat) = *(const float4*)(W + kb * NOUT + flat);
        }
        __syncthreads();

#pragma unroll
        for (int k = 0; k < KB; ++k) {
            float4 xv = *(const float4*)(Xt + k * LDR + tr * 4);
            float xs[4] = {xv.x, xv.y, xv.z, xv.w};
            const float* wp = Ws + k * NOUT + tc * CM;
            float wv[CM];
#pragma unroll
            for (int j = 0; j < CM; ++j) wv[j] = wp[j];
#pragma unroll
            for (int i = 0; i < 4; ++i)
#pragma unroll
                for (int j = 0; j < CM; ++j) acc[i][j] = fmaf(xs[i], wv[j], acc[i][j]);
        }
        __syncthreads();
    }

#pragma unroll
    for (int i = 0; i < 4; ++i) {
        int r = rowBase + tr * 4 + i;
        if (r < N) {
            float d = dinv[r];
            float* pm = outM + (size_t)r * NOUT + tc * CM;
#pragma unroll
            for (int j = 0; j < CM; ++j) pm[j] = acc[i][j] * d;
        }
    }
}

// ---------------------------------------------------------------- pull aggregation (CSR, no atomics)
// h[node] = relu( dinv[node] * ( m'[node] + sum_e w_e * m'[src_e] ) + bias )
// NOUT/4 lanes per node, float4 register accumulator, one coalesced write.
template <int NOUT>
__global__ __launch_bounds__(256) void pull_kernel(
    const int* __restrict__ rowptr, const int2* __restrict__ es,
    const float* __restrict__ mprime, const float* __restrict__ dinv,
    const float* __restrict__ bias, float* __restrict__ h, int N) {
    constexpr int SH = (NOUT == 64) ? 4 : 3;   // log2(NOUT/4)
    int gid = blockIdx.x * 256 + threadIdx.x;
    int node = gid >> SH;
    int c = gid & ((1 << SH) - 1);
    if (node >= N) return;

    float4 acc = *(const float4*)(mprime + (size_t)node * NOUT + c * 4);  // self loop
    int b = rowptr[node], e = rowptr[node + 1];
    for (int p = b; p < e; ++p) {
        int2 ed = es[p];
        float w = __int_as_float(ed.y);
        float4 v = *(const float4*)(mprime + (size_t)ed.x * NOUT + c * 4);
        acc.x = fmaf(w, v.x, acc.x);
        acc.y = fmaf(w, v.y, acc.y);
        acc.z = fmaf(w, v.z, acc.z);
        acc.w = fmaf(w, v.w, acc.w);
    }
    float d = dinv[node];
    float4 bb = *(const float4*)(bias + c * 4);
    float4 o;
    o.x = fmaxf(fmaf(d, acc.x, bb.x), 0.f);
    o.y = fmaxf(fmaf(d, acc.y, bb.y), 0.f);
    o.z = fmaxf(fmaf(d, acc.z, bb.z), 0.f);
    o.w = fmaxf(fmaf(d, acc.w, bb.w), 0.f);
    *(float4*)(h + (size_t)node * NOUT + c * 4) = o;
}

// ---------------------------------------------------------------- sum-pool (ngi sorted -> run-length)
// thread: feature quad c (8 per node), 16 consecutive nodes; flush atomic on graph change
__global__ __launch_bounds__(256) void pool_kernel(
    const float* __restrict__ h2, const int* __restrict__ ngi,
    float* __restrict__ g, int N) {
    int t = blockIdx.x * 256 + threadIdx.x;
    int grp = t >> 3;        // node-chunk index
    int c = t & 7;           // feature quad
    int n0 = grp * 16;
    if (n0 >= N) return;
    int nEnd = min(n0 + 16, N);
    int curg = ngi[n0];
    float4 acc = make_float4(0.f, 0.f, 0.f, 0.f);
    for (int n = n0; n < nEnd; ++n) {
        int gi = ngi[n];
        if (gi != curg) {
            float* gp = g + curg * 32 + c * 4;
            atomicAdd(gp + 0, acc.x); atomicAdd(gp + 1, acc.y);
            atomicAdd(gp + 2, acc.z); atomicAdd(gp + 3, acc.w);
            acc = make_float4(0.f, 0.f, 0.f, 0.f);
            curg = gi;
        }
        float4 v = *(const float4*)(h2 + (size_t)n * 32 + c * 4);
        acc.x += v.x; acc.y += v.y; acc.z += v.z; acc.w += v.w;
    }
    float* gp = g + curg * 32 + c * 4;
    atomicAdd(gp + 0, acc.x); atomicAdd(gp + 1, acc.y);
    atomicAdd(gp + 2, acc.z); atomicAdd(gp + 3, acc.w);
}

// ---------------------------------------------------------------- MLP head
__global__ __launch_bounds__(128) void mlp_kernel(
    const float* __restrict__ g, const float* __restrict__ Wm1,
    const float* __restrict__ bm1, const float* __restrict__ Wm2,
    const float* __restrict__ bm2, float* __restrict__ out) {
    __shared__ float sg[32];
    __shared__ float st[128];
    int b = blockIdx.x, t = threadIdx.x;
    if (t < 32) sg[t] = g[b * 32 + t];
    __syncthreads();
    float acc = bm1[t];
#pragma unroll
    for (int k = 0; k < 32; ++k) acc = fmaf(sg[k], Wm1[k * 128 + t], acc);
    st[t] = fmaxf(acc, 0.f);
    __syncthreads();
    if (t < 2) {
        float o = bm2[t];
#pragma unroll
        for (int k = 0; k < 128; ++k) o = fmaf(st[k], Wm2[k * 2 + t], o);
        out[b * 2 + t] = o;
    }
}

// ---------------------------------------------------------------- launch

extern "C" void kernel_launch(void* const* d_in, const int* in_sizes, int n_in,
                              void* d_out, int out_size, void* d_ws, size_t ws_size,
                              hipStream_t stream) {
    const float* x   = (const float*)d_in[0];
    const int*   ei  = (const int*)d_in[1];
    const float* ew  = (const float*)d_in[2];
    const int*   ngi = (const int*)d_in[3];
    const float* W0  = (const float*)d_in[4];
    const float* b0  = (const float*)d_in[5];
    const float* W1  = (const float*)d_in[6];
    const float* b1  = (const float*)d_in[7];
    const float* Wm1 = (const float*)d_in[8];
    const float* bm1 = (const float*)d_in[9];
    const float* Wm2 = (const float*)d_in[10];
    const float* bm2 = (const float*)d_in[11];
    float* out = (float*)d_out;

    const int N = in_sizes[0] / F_IN;       // 100000
    const int E = in_sizes[1] / 2;          // 1600000
    const int G = out_size / 2;             // 1000
    const int* srcp = ei;
    const int* dstp = ei + E;
    const int NB = (N + 255) / 256;         // scan blocks (391)

    // workspace layout (256B-aligned chunks)
    char* wsb = (char*)d_ws;
    size_t off = 0;
    auto alloc = [&](size_t bytes) {
        char* p = wsb + off;
        off += (bytes + 255) & ~(size_t)255;
        return p;
    };
    float* dinv   = (float*)alloc((size_t)N * 4);
    int*   cnt    = (int*)  alloc((size_t)N * 4);
    int*   rowptr = (int*)  alloc((size_t)(N + 1) * 4);
    int*   cursor = (int*)  alloc((size_t)N * 4);
    int*   part   = (int*)  alloc((size_t)(NB + 1) * 4);
    int2*  es     = (int2*) alloc((size_t)E * 8);
    float* A      = (float*)alloc((size_t)N * 64 * 4);  // m0' | later m1'(lo) + h2(hi)
    float* B      = (float*)alloc((size_t)N * 64 * 4);  // h1
    float* Gbuf   = (float*)alloc((size_t)G * 32 * 4);
    float* m1p = A;                     // N*32
    float* h2  = A + (size_t)N * 32;    // N*32

    // 1. CSR build (counting sort by dst)
    zero_i_kernel<<<NB, 256, 0, stream>>>(cnt, N);
    count_kernel<<<(E + 255) / 256, 256, 0, stream>>>(dstp, cnt, E);
    scan_block_kernel<<<NB, 256, 0, stream>>>(cnt, rowptr, part, N);
    scan_part_kernel<<<1, 512, 0, stream>>>(part, NB);
    scan_add_kernel<<<(N + 256) / 256, 256, 0, stream>>>(rowptr, cursor, part, N, NB);
    place_kernel<<<(E + 255) / 256, 256, 0, stream>>>(srcp, dstp, ew, cursor, es, E);

    // 2. dinv from CSR
    dinv_kernel<<<NB, 256, 0, stream>>>(rowptr, es, dinv, N);

    // 3. layer 1: m0' = dinv*(x@W0) -> A; pull-aggregate -> h1 in B
    gemm_scale_kernel<128, 64><<<(N + 63) / 64, 256, 0, stream>>>(x, W0, dinv, A, N);
    pull_kernel<64><<<(N * 16 + 255) / 256, 256, 0, stream>>>(rowptr, es, A, dinv, b0, B, N);

    // 4. layer 2: m1' = dinv*(h1@W1) -> m1p; pull-aggregate -> h2
    gemm_scale_kernel<64, 32><<<(N + 63) / 64, 256, 0, stream>>>(B, W1, dinv, m1p, N);
    pull_kernel<32><<<(N * 8 + 255) / 256, 256, 0, stream>>>(rowptr, es, m1p, dinv, b1, h2, N);

    // 5. pool + MLP head
    zero_f_kernel<<<(G * 32 + 255) / 256, 256, 0, stream>>>(Gbuf, G * 32);
    pool_kernel<<<((N + 15) / 16 * 8 + 255) / 256, 256, 0, stream>>>(h2, ngi, Gbuf, N);
    mlp_kernel<<<G, 128, 0, stream>>>(Gbuf, Wm1, bm1, Wm2, bm2, out);
}

// Round 4
// 366.513 us; speedup vs baseline: 6.3660x; 1.3389x over previous
//
#include <hip/hip_runtime.h>
#include <hip/hip_bf16.h>

#define F_IN 128
#define NPB 256      // dst nodes per bucket
#define NPB_SH 8
#define MAXB 512     // static LDS bucket-array size (requires N <= 131072)
#define CHUNK 8192   // edges per histogram/scatter block

// ---------------------------------------------------------------- small utils

__global__ __launch_bounds__(256) void zero_i_kernel(int* p, int n) {
    int i = blockIdx.x * 256 + threadIdx.x;
    if (i < n) p[i] = 0;
}

__global__ __launch_bounds__(256) void zero_f_kernel(float* p, int n) {
    int i = blockIdx.x * 256 + threadIdx.x;
    if (i < n) p[i] = 0.f;
}

// ---------------------------------------------------------------- pass 1a: per-chunk histogram + reservation
// blockres[blk*nbucket + b] = starting offset (bucket-relative) of this block's
// bucket-b edges. Written unconditionally so pass 1b can read it blindly.
__global__ __launch_bounds__(256) void hist_kernel(
    const int* __restrict__ dst, int* __restrict__ gcursor,
    int* __restrict__ blockres, int E, int nbucket) {
    __shared__ int hist[MAXB];
    const int tid = threadIdx.x;
    const int e0 = blockIdx.x * CHUNK;
    const int e1 = min(e0 + CHUNK, E);
    for (int b = tid; b < nbucket; b += 256) hist[b] = 0;
    __syncthreads();
    for (int e = e0 + tid; e < e1; e += 256)
        atomicAdd(&hist[dst[e] >> NPB_SH], 1);
    __syncthreads();
    int* res = blockres + (size_t)blockIdx.x * nbucket;
    for (int b = tid; b < nbucket; b += 256)
        res[b] = atomicAdd(&gcursor[b], hist[b]);
}

// exclusive scan of bucket counts (nb <= 512), bbase[nb] = total
__global__ __launch_bounds__(512) void bucket_scan_kernel(const int* __restrict__ gcursor,
                                                          int* __restrict__ bbase, int nb) {
    __shared__ int tmp[512];
    int i = threadIdx.x;
    int v = (i < nb) ? gcursor[i] : 0;
    tmp[i] = v;
    __syncthreads();
    for (int o = 1; o < 512; o <<= 1) {
        int t = (i >= o) ? tmp[i - o] : 0;
        __syncthreads();
        tmp[i] += t;
        __syncthreads();
    }
    if (i < nb) bbase[i] = tmp[i] - v;
    if (i == nb - 1) bbase[nb] = tmp[i];
}

// ---------------------------------------------------------------- pass 1b: place edges into bucket segments
// tmp entry: {src | (dst&255)<<17, bits(w)}  (src < 2^17)
__global__ __launch_bounds__(256) void scatter_bucket_kernel(
    const int* __restrict__ src, const int* __restrict__ dst,
    const float* __restrict__ ew, const int* __restrict__ bbase,
    const int* __restrict__ blockres, int2* __restrict__ tmp,
    int E, int nbucket) {
    __shared__ int base[MAXB];   // absolute base for this block's bucket-b run
    __shared__ int cur[MAXB];
    const int tid = threadIdx.x;
    const int e0 = blockIdx.x * CHUNK;
    const int e1 = min(e0 + CHUNK, E);
    const int* res = blockres + (size_t)blockIdx.x * nbucket;
    for (int b = tid; b < nbucket; b += 256) {
        base[b] = bbase[b] + res[b];
        cur[b] = 0;
    }
    __syncthreads();
    for (int e = e0 + tid; e < e1; e += 256) {
        int d = dst[e];
        int b = d >> NPB_SH;
        int r = atomicAdd(&cur[b], 1);
        tmp[base[b] + r] =
            make_int2(src[e] | ((d & (NPB - 1)) << 17), __float_as_int(ew[e]));
    }
}

// ---------------------------------------------------------------- pass 2: per-bucket CSR + rowptr + dinv
// one block per bucket; all es writes land in one contiguous ~33KB region
__global__ __launch_bounds__(256) void csr_kernel(
    const int2* __restrict__ tmp, const int* __restrict__ bbase,
    int2* __restrict__ es, int* __restrict__ rowptr, float* __restrict__ dinv,
    int N, int E) {
    __shared__ int cnt[256];
    __shared__ float dw[256];
    __shared__ int off[256];
    __shared__ int cur[256];
    const int t = threadIdx.x;
    const int n0 = blockIdx.x << NPB_SH;
    cnt[t] = 0;
    dw[t] = 0.f;
    __syncthreads();
    const int bb = bbase[blockIdx.x], be = bbase[blockIdx.x + 1];
    for (int p = bb + t; p < be; p += 256) {
        int2 e = tmp[p];
        int d = e.x >> 17;
        atomicAdd(&cnt[d], 1);
        atomicAdd(&dw[d], __int_as_float(e.y));
    }
    __syncthreads();
    int v = cnt[t];
    off[t] = v;
    __syncthreads();
    for (int o = 1; o < 256; o <<= 1) {
        int x = (t >= o) ? off[t - o] : 0;
        __syncthreads();
        off[t] += x;
        __syncthreads();
    }
    int excl = off[t] - v;
    cur[t] = excl;
    int n = n0 + t;
    if (n < N) {
        rowptr[n] = bb + excl;
        dinv[n] = rsqrtf(fmaxf(1.f + dw[t], 1e-12f));
    }
    if (blockIdx.x == 0 && t == 0) rowptr[N] = E;
    __syncthreads();
    for (int p = bb + t; p < be; p += 256) {
        int2 e = tmp[p];
        int d = e.x >> 17;
        int r = atomicAdd(&cur[d], 1);
        es[bb + r] = make_int2(e.x & 0x1FFFF, e.y);
    }
}

// ---------------------------------------------------------------- GEMM + dinv scale
// outM[row] = dinv[row] * (X[row,:] @ W)
template <int K, int NOUT>
__global__ __launch_bounds__(256) void gemm_scale_kernel(
    const float* __restrict__ X, const float* __restrict__ W,
    const float* __restrict__ dinv, float* __restrict__ outM, int N) {
    constexpr int ROWS = 64;
    constexpr int KB = 64;
    constexpr int LDR = ROWS + 4;
    constexpr int CM = NOUT / 16;

    __shared__ float Xt[KB * LDR];   // transposed: [k][row]
    __shared__ float Ws[KB * NOUT];  // [k][col]

    const int tid = threadIdx.x;
    const int tc = tid & 15;
    const int tr = tid >> 4;
    const int rowBase = blockIdx.x * ROWS;

    float acc[4][CM];
#pragma unroll
    for (int i = 0; i < 4; ++i)
#pragma unroll
        for (int j = 0; j < CM; ++j) acc[i][j] = 0.f;

    for (int kb = 0; kb < K; kb += KB) {
#pragma unroll
        for (int it = 0; it < (ROWS * KB) / (256 * 4); ++it) {
            int flat = it * 1024 + tid * 4;
            int r = flat >> 6;
            int c = flat & 63;
            int grow = rowBase + r;
            float4 v = make_float4(0.f, 0.f, 0.f, 0.f);
            if (grow < N) v = *(const float4*)(X + (size_t)grow * K + kb + c);
            Xt[(c + 0) * LDR + r] = v.x;
            Xt[(c + 1) * LDR + r] = v.y;
            Xt[(c + 2) * LDR + r] = v.z;
            Xt[(c + 3) * LDR + r] = v.w;
        }
#pragma unroll
        for (int it = 0; it < (KB * NOUT) / (256 * 4); ++it) {
            int flat = it * 1024 + tid * 4;
            *(float4*)(Ws + flat) = *(const float4*)(W + kb * NOUT + flat);
        }
        __syncthreads();

#pragma unroll
        for (int k = 0; k < KB; ++k) {
            float4 xv = *(const float4*)(Xt + k * LDR + tr * 4);
            float xs[4] = {xv.x, xv.y, xv.z, xv.w};
            const float* wp = Ws + k * NOUT + tc * CM;
            float wv[CM];
#pragma unroll
            for (int j = 0; j < CM; ++j) wv[j] = wp[j];
#pragma unroll
            for (int i = 0; i < 4; ++i)
#pragma unroll
                for (int j = 0; j < CM; ++j) acc[i][j] = fmaf(xs[i], wv[j], acc[i][j]);
        }
        __syncthreads();
    }

#pragma unroll
    for (int i = 0; i < 4; ++i) {
        int r = rowBase + tr * 4 + i;
        if (r < N) {
            float d = dinv[r];
            float* pm = outM + (size_t)r * NOUT + tc * CM;
#pragma unroll
            for (int j = 0; j < CM; ++j) pm[j] = acc[i][j] * d;
        }
    }
}

// ---------------------------------------------------------------- pull aggregation (CSR, no atomics)
// h[node] = relu( dinv[node] * ( m'[node] + sum_e w_e * m'[src_e] ) + bias )
template <int NOUT>
__global__ __launch_bounds__(256) void pull_kernel(
    const int* __restrict__ rowptr, const int2* __restrict__ es,
    const float* __restrict__ mprime, const float* __restrict__ dinv,
    const float* __restrict__ bias, float* __restrict__ h, int N) {
    constexpr int SH = (NOUT == 64) ? 4 : 3;   // log2(NOUT/4)
    int gid = blockIdx.x * 256 + threadIdx.x;
    int node = gid >> SH;
    int c = gid & ((1 << SH) - 1);
    if (node >= N) return;

    float4 acc = *(const float4*)(mprime + (size_t)node * NOUT + c * 4);  // self loop
    int b = rowptr[node], e = rowptr[node + 1];
    for (int p = b; p < e; ++p) {
        int2 ed = es[p];
        float w = __int_as_float(ed.y);
        float4 v = *(const float4*)(mprime + (size_t)ed.x * NOUT + c * 4);
        acc.x = fmaf(w, v.x, acc.x);
        acc.y = fmaf(w, v.y, acc.y);
        acc.z = fmaf(w, v.z, acc.z);
        acc.w = fmaf(w, v.w, acc.w);
    }
    float d = dinv[node];
    float4 bb = *(const float4*)(bias + c * 4);
    float4 o;
    o.x = fmaxf(fmaf(d, acc.x, bb.x), 0.f);
    o.y = fmaxf(fmaf(d, acc.y, bb.y), 0.f);
    o.z = fmaxf(fmaf(d, acc.z, bb.z), 0.f);
    o.w = fmaxf(fmaf(d, acc.w, bb.w), 0.f);
    *(float4*)(h + (size_t)node * NOUT + c * 4) = o;
}

// ---------------------------------------------------------------- sum-pool (ngi sorted -> run-length)
__global__ __launch_bounds__(256) void pool_kernel(
    const float* __restrict__ h2, const int* __restrict__ ngi,
    float* __restrict__ g, int N) {
    int t = blockIdx.x * 256 + threadIdx.x;
    int grp = t >> 3;        // node-chunk index
    int c = t & 7;           // feature quad
    int n0 = grp * 16;
    if (n0 >= N) return;
    int nEnd = min(n0 + 16, N);
    int curg = ngi[n0];
    float4 acc = make_float4(0.f, 0.f, 0.f, 0.f);
    for (int n = n0; n < nEnd; ++n) {
        int gi = ngi[n];
        if (gi != curg) {
            float* gp = g + curg * 32 + c * 4;
            atomicAdd(gp + 0, acc.x); atomicAdd(gp + 1, acc.y);
            atomicAdd(gp + 2, acc.z); atomicAdd(gp + 3, acc.w);
            acc = make_float4(0.f, 0.f, 0.f, 0.f);
            curg = gi;
        }
        float4 v = *(const float4*)(h2 + (size_t)n * 32 + c * 4);
        acc.x += v.x; acc.y += v.y; acc.z += v.z; acc.w += v.w;
    }
    float* gp = g + curg * 32 + c * 4;
    atomicAdd(gp + 0, acc.x); atomicAdd(gp + 1, acc.y);
    atomicAdd(gp + 2, acc.z); atomicAdd(gp + 3, acc.w);
}

// ---------------------------------------------------------------- MLP head
__global__ __launch_bounds__(128) void mlp_kernel(
    const float* __restrict__ g, const float* __restrict__ Wm1,
    const float* __restrict__ bm1, const float* __restrict__ Wm2,
    const float* __restrict__ bm2, float* __restrict__ out) {
    __shared__ float sg[32];
    __shared__ float st[128];
    int b = blockIdx.x, t = threadIdx.x;
    if (t < 32) sg[t] = g[b * 32 + t];
    __syncthreads();
    float acc = bm1[t];
#pragma unroll
    for (int k = 0; k < 32; ++k) acc = fmaf(sg[k], Wm1[k * 128 + t], acc);
    st[t] = fmaxf(acc, 0.f);
    __syncthreads();
    if (t < 2) {
        float o = bm2[t];
#pragma unroll
        for (int k = 0; k < 128; ++k) o = fmaf(st[k], Wm2[k * 2 + t], o);
        out[b * 2 + t] = o;
    }
}

// ---------------------------------------------------------------- launch

extern "C" void kernel_launch(void* const* d_in, const int* in_sizes, int n_in,
                              void* d_out, int out_size, void* d_ws, size_t ws_size,
                              hipStream_t stream) {
    const float* x   = (const float*)d_in[0];
    const int*   ei  = (const int*)d_in[1];
    const float* ew  = (const float*)d_in[2];
    const int*   ngi = (const int*)d_in[3];
    const float* W0  = (const float*)d_in[4];
    const float* b0  = (const float*)d_in[5];
    const float* W1  = (const float*)d_in[6];
    const float* b1  = (const float*)d_in[7];
    const float* Wm1 = (const float*)d_in[8];
    const float* bm1 = (const float*)d_in[9];
    const float* Wm2 = (const float*)d_in[10];
    const float* bm2 = (const float*)d_in[11];
    float* out = (float*)d_out;

    const int N = in_sizes[0] / F_IN;       // 100000 (< 2^17, packing requirement)
    const int E = in_sizes[1] / 2;          // 1600000
    const int G = out_size / 2;             // 1000
    const int* srcp = ei;
    const int* dstp = ei + E;
    const int NBUCKET = (N + NPB - 1) >> NPB_SH;       // 391
    const int NBLK = (E + CHUNK - 1) / CHUNK;          // 196

    // workspace layout (256B-aligned chunks)
    char* wsb = (char*)d_ws;
    size_t off = 0;
    auto alloc = [&](size_t bytes) {
        char* p = wsb + off;
        off += (bytes + 255) & ~(size_t)255;
        return p;
    };
    float* dinv     = (float*)alloc((size_t)N * 4);
    int*   gcursor  = (int*)  alloc((size_t)NBUCKET * 4);
    int*   bbase    = (int*)  alloc((size_t)(NBUCKET + 1) * 4);
    int*   rowptr   = (int*)  alloc((size_t)(N + 1) * 4);
    int*   blockres = (int*)  alloc((size_t)NBLK * NBUCKET * 4);
    int2*  es       = (int2*) alloc((size_t)E * 8);
    float* A        = (float*)alloc((size_t)N * 64 * 4);  // m0' | later m1'(lo) + h2(hi)
    float* B        = (float*)alloc((size_t)N * 64 * 4);  // h1 (tmp aliases this, dead before pull1)
    float* Gbuf     = (float*)alloc((size_t)G * 32 * 4);
    int2* tmp = (int2*)B;               // bucketed edges, E*8 <= N*64*4
    float* m1p = A;                     // N*32
    float* h2  = A + (size_t)N * 32;    // N*32

    // 1. CSR build: hist+reserve -> scan -> place -> per-bucket sort (+rowptr +dinv fused)
    zero_i_kernel<<<(NBUCKET + 255) / 256, 256, 0, stream>>>(gcursor, NBUCKET);
    hist_kernel<<<NBLK, 256, 0, stream>>>(dstp, gcursor, blockres, E, NBUCKET);
    bucket_scan_kernel<<<1, 512, 0, stream>>>(gcursor, bbase, NBUCKET);
    scatter_bucket_kernel<<<NBLK, 256, 0, stream>>>(srcp, dstp, ew, bbase, blockres, tmp, E, NBUCKET);
    csr_kernel<<<NBUCKET, 256, 0, stream>>>(tmp, bbase, es, rowptr, dinv, N, E);

    // 2. layer 1: m0' = dinv*(x@W0) -> A; pull-aggregate -> h1 in B
    gemm_scale_kernel<128, 64><<<(N + 63) / 64, 256, 0, stream>>>(x, W0, dinv, A, N);
    pull_kernel<64><<<(N * 16 + 255) / 256, 256, 0, stream>>>(rowptr, es, A, dinv, b0, B, N);

    // 3. layer 2: m1' = dinv*(h1@W1) -> m1p; pull-aggregate -> h2
    gemm_scale_kernel<64, 32><<<(N + 63) / 64, 256, 0, stream>>>(B, W1, dinv, m1p, N);
    pull_kernel<32><<<(N * 8 + 255) / 256, 256, 0, stream>>>(rowptr, es, m1p, dinv, b1, h2, N);

    // 4. pool + MLP head
    zero_f_kernel<<<(G * 32 + 255) / 256, 256, 0, stream>>>(Gbuf, G * 32);
    pool_kernel<<<((N + 15) / 16 * 8 + 255) / 256, 256, 0, stream>>>(h2, ngi, Gbuf, N);
    mlp_kernel<<<G, 128, 0, stream>>>(Gbuf, Wm1, bm1, Wm2, bm2, out);
}

// Round 5
// 347.289 us; speedup vs baseline: 6.7184x; 1.0554x over previous
//
#include <hip/hip_runtime.h>
#include <hip/hip_bf16.h>

#define F_IN 128
#define NPB 256      // dst nodes per bucket
#define NPB_SH 8
#define MAXB 512     // static LDS bucket-array size (requires N <= 131072)
#define CHUNK 8192   // edges per histogram/scatter block

// ---------------------------------------------------------------- bf16 helpers (storage only; math in fp32)

__device__ __forceinline__ float bf2f(unsigned short u) {
    return __uint_as_float(((unsigned int)u) << 16);
}
__device__ __forceinline__ unsigned short f2bf(float f) {
    unsigned int x = __float_as_uint(f);
    x += 0x7FFFu + ((x >> 16) & 1u);   // round-to-nearest-even
    return (unsigned short)(x >> 16);
}

// ---------------------------------------------------------------- pass 1a: per-chunk histogram + reservation
__global__ __launch_bounds__(256) void hist_kernel(
    const int* __restrict__ dst, int* __restrict__ gcursor,
    int* __restrict__ blockres, int E, int nbucket) {
    __shared__ int hist[MAXB];
    const int tid = threadIdx.x;
    const int e0 = blockIdx.x * CHUNK;
    const int e1 = min(e0 + CHUNK, E);
    for (int b = tid; b < nbucket; b += 256) hist[b] = 0;
    __syncthreads();
    for (int e = e0 + tid; e < e1; e += 256)
        atomicAdd(&hist[dst[e] >> NPB_SH], 1);
    __syncthreads();
    int* res = blockres + (size_t)blockIdx.x * nbucket;
    for (int b = tid; b < nbucket; b += 256)
        res[b] = atomicAdd(&gcursor[b], hist[b]);
}

// exclusive scan of bucket counts (nb <= 512), bbase[nb] = total
__global__ __launch_bounds__(512) void bucket_scan_kernel(const int* __restrict__ gcursor,
                                                          int* __restrict__ bbase, int nb) {
    __shared__ int tmp[512];
    int i = threadIdx.x;
    int v = (i < nb) ? gcursor[i] : 0;
    tmp[i] = v;
    __syncthreads();
    for (int o = 1; o < 512; o <<= 1) {
        int t = (i >= o) ? tmp[i - o] : 0;
        __syncthreads();
        tmp[i] += t;
        __syncthreads();
    }
    if (i < nb) bbase[i] = tmp[i] - v;
    if (i == nb - 1) bbase[nb] = tmp[i];
}

// ---------------------------------------------------------------- pass 1b: place edges into bucket segments
// tmp entry: {src | (dst&255)<<17, bits(w)}  (src < 2^17)
__global__ __launch_bounds__(256) void scatter_bucket_kernel(
    const int* __restrict__ src, const int* __restrict__ dst,
    const float* __restrict__ ew, const int* __restrict__ bbase,
    const int* __restrict__ blockres, int2* __restrict__ tmp,
    int E, int nbucket) {
    __shared__ int base[MAXB];
    __shared__ int cur[MAXB];
    const int tid = threadIdx.x;
    const int e0 = blockIdx.x * CHUNK;
    const int e1 = min(e0 + CHUNK, E);
    const int* res = blockres + (size_t)blockIdx.x * nbucket;
    for (int b = tid; b < nbucket; b += 256) {
        base[b] = bbase[b] + res[b];
        cur[b] = 0;
    }
    __syncthreads();
    for (int e = e0 + tid; e < e1; e += 256) {
        int d = dst[e];
        int b = d >> NPB_SH;
        int r = atomicAdd(&cur[b], 1);
        tmp[base[b] + r] =
            make_int2(src[e] | ((d & (NPB - 1)) << 17), __float_as_int(ew[e]));
    }
}

// ---------------------------------------------------------------- pass 2: per-bucket CSR + rowptr + dinv
__global__ __launch_bounds__(256) void csr_kernel(
    const int2* __restrict__ tmp, const int* __restrict__ bbase,
    int2* __restrict__ es, int* __restrict__ rowptr, float* __restrict__ dinv,
    int N, int E) {
    __shared__ int cnt[256];
    __shared__ float dw[256];
    __shared__ int off[256];
    __shared__ int cur[256];
    const int t = threadIdx.x;
    const int n0 = blockIdx.x << NPB_SH;
    cnt[t] = 0;
    dw[t] = 0.f;
    __syncthreads();
    const int bb = bbase[blockIdx.x], be = bbase[blockIdx.x + 1];
    for (int p = bb + t; p < be; p += 256) {
        int2 e = tmp[p];
        int d = e.x >> 17;
        atomicAdd(&cnt[d], 1);
        atomicAdd(&dw[d], __int_as_float(e.y));
    }
    __syncthreads();
    int v = cnt[t];
    off[t] = v;
    __syncthreads();
    for (int o = 1; o < 256; o <<= 1) {
        int x = (t >= o) ? off[t - o] : 0;
        __syncthreads();
        off[t] += x;
        __syncthreads();
    }
    int excl = off[t] - v;
    cur[t] = excl;
    int n = n0 + t;
    if (n < N) {
        rowptr[n] = bb + excl;
        dinv[n] = rsqrtf(fmaxf(1.f + dw[t], 1e-12f));
    }
    if (blockIdx.x == 0 && t == 0) rowptr[N] = E;
    __syncthreads();
    for (int p = bb + t; p < be; p += 256) {
        int2 e = tmp[p];
        int d = e.x >> 17;
        int r = atomicAdd(&cur[d], 1);
        es[bb + r] = make_int2(e.x & 0x1FFFF, e.y);
    }
}

// ---------------------------------------------------------------- GEMM + dinv scale -> bf16
// outM[row] = bf16( dinv[row] * (X[row,:] @ W) )
template <int K, int NOUT>
__global__ __launch_bounds__(256) void gemm_scale_kernel(
    const float* __restrict__ X, const float* __restrict__ W,
    const float* __restrict__ dinv, unsigned short* __restrict__ outM, int N) {
    constexpr int ROWS = 64;
    constexpr int KB = 64;
    constexpr int LDR = ROWS + 4;
    constexpr int CM = NOUT / 16;

    __shared__ float Xt[KB * LDR];   // transposed: [k][row]
    __shared__ float Ws[KB * NOUT];  // [k][col]

    const int tid = threadIdx.x;
    const int tc = tid & 15;
    const int tr = tid >> 4;
    const int rowBase = blockIdx.x * ROWS;

    float acc[4][CM];
#pragma unroll
    for (int i = 0; i < 4; ++i)
#pragma unroll
        for (int j = 0; j < CM; ++j) acc[i][j] = 0.f;

    for (int kb = 0; kb < K; kb += KB) {
#pragma unroll
        for (int it = 0; it < (ROWS * KB) / (256 * 4); ++it) {
            int flat = it * 1024 + tid * 4;
            int r = flat >> 6;
            int c = flat & 63;
            int grow = rowBase + r;
            float4 v = make_float4(0.f, 0.f, 0.f, 0.f);
            if (grow < N) v = *(const float4*)(X + (size_t)grow * K + kb + c);
            Xt[(c + 0) * LDR + r] = v.x;
            Xt[(c + 1) * LDR + r] = v.y;
            Xt[(c + 2) * LDR + r] = v.z;
            Xt[(c + 3) * LDR + r] = v.w;
        }
#pragma unroll
        for (int it = 0; it < (KB * NOUT) / (256 * 4); ++it) {
            int flat = it * 1024 + tid * 4;
            *(float4*)(Ws + flat) = *(const float4*)(W + kb * NOUT + flat);
        }
        __syncthreads();

#pragma unroll
        for (int k = 0; k < KB; ++k) {
            float4 xv = *(const float4*)(Xt + k * LDR + tr * 4);
            float xs[4] = {xv.x, xv.y, xv.z, xv.w};
            const float* wp = Ws + k * NOUT + tc * CM;
            float wv[CM];
#pragma unroll
            for (int j = 0; j < CM; ++j) wv[j] = wp[j];
#pragma unroll
            for (int i = 0; i < 4; ++i)
#pragma unroll
                for (int j = 0; j < CM; ++j) acc[i][j] = fmaf(xs[i], wv[j], acc[i][j]);
        }
        __syncthreads();
    }

#pragma unroll
    for (int i = 0; i < 4; ++i) {
        int r = rowBase + tr * 4 + i;
        if (r < N) {
            float d = dinv[r];
            unsigned short* pm = outM + (size_t)r * NOUT + tc * CM;
            unsigned short bv[CM];
#pragma unroll
            for (int j = 0; j < CM; ++j) bv[j] = f2bf(acc[i][j] * d);
            if (CM == 4) *(ushort4*)pm = make_ushort4(bv[0], bv[1], bv[2], bv[3]);
            else         *(ushort2*)pm = make_ushort2(bv[0], bv[1]);
        }
    }
}

// ---------------------------------------------------------------- pull aggregation (bf16 gather, fp32 accum)
// h[node] = relu( dinv[node] * ( m'[node] + sum_e w_e * m'[src_e] ) + bias )
template <int NOUT>
__global__ __launch_bounds__(256) void pull_kernel(
    const int* __restrict__ rowptr, const int2* __restrict__ es,
    const unsigned short* __restrict__ mprime, const float* __restrict__ dinv,
    const float* __restrict__ bias, float* __restrict__ h, int N) {
    constexpr int SH = (NOUT == 64) ? 4 : 3;   // log2(NOUT/4)
    int gid = blockIdx.x * 256 + threadIdx.x;
    int node = gid >> SH;
    int c = gid & ((1 << SH) - 1);
    if (node >= N) return;

    ushort4 su = *(const ushort4*)(mprime + (size_t)node * NOUT + c * 4);
    float4 acc = make_float4(bf2f(su.x), bf2f(su.y), bf2f(su.z), bf2f(su.w));
    int b = rowptr[node], e = rowptr[node + 1];
    for (int p = b; p < e; ++p) {
        int2 ed = es[p];
        float w = __int_as_float(ed.y);
        ushort4 u = *(const ushort4*)(mprime + (size_t)ed.x * NOUT + c * 4);
        acc.x = fmaf(w, bf2f(u.x), acc.x);
        acc.y = fmaf(w, bf2f(u.y), acc.y);
        acc.z = fmaf(w, bf2f(u.z), acc.z);
        acc.w = fmaf(w, bf2f(u.w), acc.w);
    }
    float d = dinv[node];
    float4 bb = *(const float4*)(bias + c * 4);
    float4 o;
    o.x = fmaxf(fmaf(d, acc.x, bb.x), 0.f);
    o.y = fmaxf(fmaf(d, acc.y, bb.y), 0.f);
    o.z = fmaxf(fmaf(d, acc.z, bb.z), 0.f);
    o.w = fmaxf(fmaf(d, acc.w, bb.w), 0.f);
    *(float4*)(h + (size_t)node * NOUT + c * 4) = o;
}

// ---------------------------------------------------------------- pull2 + fused sum-pool (NOUT=32)
// computes h2[node] in registers, then run-length segmented reduce over the
// block's 32 nodes (ngi sorted) -> few atomics per (graph, feature-quad)
__global__ __launch_bounds__(256) void pull2_pool_kernel(
    const int* __restrict__ rowptr, const int2* __restrict__ es,
    const unsigned short* __restrict__ mprime, const float* __restrict__ dinv,
    const float* __restrict__ bias, const int* __restrict__ ngi,
    float* __restrict__ g, int N) {
    constexpr int NOUT = 32;
    __shared__ float4 sh[32][8];
    __shared__ int sg[32];
    int gid = blockIdx.x * 256 + threadIdx.x;
    int node = gid >> 3;
    int c = gid & 7;
    int nl = threadIdx.x >> 3;
    bool valid = node < N;

    float4 o = make_float4(0.f, 0.f, 0.f, 0.f);
    if (valid) {
        ushort4 su = *(const ushort4*)(mprime + (size_t)node * NOUT + c * 4);
        float4 acc = make_float4(bf2f(su.x), bf2f(su.y), bf2f(su.z), bf2f(su.w));
        int b = rowptr[node], e = rowptr[node + 1];
        for (int p = b; p < e; ++p) {
            int2 ed = es[p];
            float w = __int_as_float(ed.y);
            ushort4 u = *(const ushort4*)(mprime + (size_t)ed.x * NOUT + c * 4);
            acc.x = fmaf(w, bf2f(u.x), acc.x);
            acc.y = fmaf(w, bf2f(u.y), acc.y);
            acc.z = fmaf(w, bf2f(u.z), acc.z);
            acc.w = fmaf(w, bf2f(u.w), acc.w);
        }
        float d = dinv[node];
        float4 bb = *(const float4*)(bias + c * 4);
        o.x = fmaxf(fmaf(d, acc.x, bb.x), 0.f);
        o.y = fmaxf(fmaf(d, acc.y, bb.y), 0.f);
        o.z = fmaxf(fmaf(d, acc.z, bb.z), 0.f);
        o.w = fmaxf(fmaf(d, acc.w, bb.w), 0.f);
    }
    sh[nl][c] = o;
    if (c == 0) sg[nl] = valid ? ngi[node] : -1;
    __syncthreads();

    int gidx = sg[nl];
    if (gidx >= 0 && (nl == 0 || sg[nl - 1] != gidx)) {   // head of run
        float4 a = sh[nl][c];
        for (int m = nl + 1; m < 32 && sg[m] == gidx; ++m) {
            float4 bx = sh[m][c];
            a.x += bx.x; a.y += bx.y; a.z += bx.z; a.w += bx.w;
        }
        float* gp = g + gidx * 32 + c * 4;
        atomicAdd(gp + 0, a.x); atomicAdd(gp + 1, a.y);
        atomicAdd(gp + 2, a.z); atomicAdd(gp + 3, a.w);
    }
}

// ---------------------------------------------------------------- MLP head
__global__ __launch_bounds__(128) void mlp_kernel(
    const float* __restrict__ g, const float* __restrict__ Wm1,
    const float* __restrict__ bm1, const float* __restrict__ Wm2,
    const float* __restrict__ bm2, float* __restrict__ out) {
    __shared__ float sg[32];
    __shared__ float st[128];
    int b = blockIdx.x, t = threadIdx.x;
    if (t < 32) sg[t] = g[b * 32 + t];
    __syncthreads();
    float acc = bm1[t];
#pragma unroll
    for (int k = 0; k < 32; ++k) acc = fmaf(sg[k], Wm1[k * 128 + t], acc);
    st[t] = fmaxf(acc, 0.f);
    __syncthreads();
    if (t < 2) {
        float o = bm2[t];
#pragma unroll
        for (int k = 0; k < 128; ++k) o = fmaf(st[k], Wm2[k * 2 + t], o);
        out[b * 2 + t] = o;
    }
}

// ---------------------------------------------------------------- launch

extern "C" void kernel_launch(void* const* d_in, const int* in_sizes, int n_in,
                              void* d_out, int out_size, void* d_ws, size_t ws_size,
                              hipStream_t stream) {
    const float* x   = (const float*)d_in[0];
    const int*   ei  = (const int*)d_in[1];
    const float* ew  = (const float*)d_in[2];
    const int*   ngi = (const int*)d_in[3];
    const float* W0  = (const float*)d_in[4];
    const float* b0  = (const float*)d_in[5];
    const float* W1  = (const float*)d_in[6];
    const float* b1  = (const float*)d_in[7];
    const float* Wm1 = (const float*)d_in[8];
    const float* bm1 = (const float*)d_in[9];
    const float* Wm2 = (const float*)d_in[10];
    const float* bm2 = (const float*)d_in[11];
    float* out = (float*)d_out;

    const int N = in_sizes[0] / F_IN;       // 100000 (< 2^17, packing requirement)
    const int E = in_sizes[1] / 2;          // 1600000
    const int G = out_size / 2;             // 1000
    const int* srcp = ei;
    const int* dstp = ei + E;
    const int NBUCKET = (N + NPB - 1) >> NPB_SH;       // 391
    const int NBLK = (E + CHUNK - 1) / CHUNK;          // 196

    // workspace layout (256B-aligned chunks)
    char* wsb = (char*)d_ws;
    size_t off = 0;
    auto alloc = [&](size_t bytes) {
        char* p = wsb + off;
        off += (bytes + 255) & ~(size_t)255;
        return p;
    };
    float* dinv     = (float*)alloc((size_t)N * 4);
    int*   gcursor  = (int*)  alloc((size_t)NBUCKET * 4);
    int*   bbase    = (int*)  alloc((size_t)(NBUCKET + 1) * 4);
    int*   rowptr   = (int*)  alloc((size_t)(N + 1) * 4);
    int*   blockres = (int*)  alloc((size_t)NBLK * NBUCKET * 4);
    int2*  es       = (int2*) alloc((size_t)E * 8);
    unsigned short* M = (unsigned short*)alloc((size_t)N * 64 * 2);  // m0' / m1' (bf16)
    float* B        = (float*)alloc((size_t)N * 64 * 4);  // h1 fp32 (tmp aliases, dead before pull1)
    float* Gbuf     = (float*)alloc((size_t)G * 32 * 4);
    int2* tmp = (int2*)B;               // bucketed edges, E*8 <= N*64*4
    unsigned short* m1p = M;            // N*32 bf16 (overwrites m0', dead after pull1)

    // 1. CSR build: hist+reserve -> scan -> place -> per-bucket sort (+rowptr +dinv fused)
    hipMemsetAsync(gcursor, 0, (size_t)NBUCKET * 4, stream);
    hist_kernel<<<NBLK, 256, 0, stream>>>(dstp, gcursor, blockres, E, NBUCKET);
    bucket_scan_kernel<<<1, 512, 0, stream>>>(gcursor, bbase, NBUCKET);
    scatter_bucket_kernel<<<NBLK, 256, 0, stream>>>(srcp, dstp, ew, bbase, blockres, tmp, E, NBUCKET);
    csr_kernel<<<NBUCKET, 256, 0, stream>>>(tmp, bbase, es, rowptr, dinv, N, E);

    // 2. layer 1: m0' = bf16(dinv*(x@W0)) -> M; pull-aggregate -> h1 fp32 in B
    gemm_scale_kernel<128, 64><<<(N + 63) / 64, 256, 0, stream>>>(x, W0, dinv, M, N);
    pull_kernel<64><<<(N * 16 + 255) / 256, 256, 0, stream>>>(rowptr, es, M, dinv, b0, B, N);

    // 3. layer 2: m1' = bf16(dinv*(h1@W1)) -> m1p; pull + fused sum-pool -> Gbuf
    gemm_scale_kernel<64, 32><<<(N + 63) / 64, 256, 0, stream>>>(B, W1, dinv, m1p, N);
    hipMemsetAsync(Gbuf, 0, (size_t)G * 32 * 4, stream);
    pull2_pool_kernel<<<(N * 8 + 255) / 256, 256, 0, stream>>>(rowptr, es, m1p, dinv, b1, ngi, Gbuf, N);

    // 4. MLP head
    mlp_kernel<<<G, 128, 0, stream>>>(Gbuf, Wm1, bm1, Wm2, bm2, out);
}

// Round 6
// 335.334 us; speedup vs baseline: 6.9579x; 1.0356x over previous
//
#include <hip/hip_runtime.h>
#include <hip/hip_bf16.h>

#define F_IN 128
#define NPB 256      // dst nodes per bucket
#define NPB_SH 8
#define MAXB 512     // static LDS bucket-array size (requires N <= 131072)
#define CHUNK 8192   // edges per histogram/scatter block

typedef __attribute__((ext_vector_type(8))) short short8;   // 8 bf16 (4 VGPRs)
typedef __attribute__((ext_vector_type(4))) float f32x4;    // MFMA accumulator

// ---------------------------------------------------------------- bf16 helpers (storage; math in fp32)

__device__ __forceinline__ float bf2f(unsigned short u) {
    return __uint_as_float(((unsigned int)u) << 16);
}
__device__ __forceinline__ unsigned short f2bf(float f) {
    unsigned int x = __float_as_uint(f);
    x += 0x7FFFu + ((x >> 16) & 1u);   // round-to-nearest-even
    return (unsigned short)(x >> 16);
}

// ---------------------------------------------------------------- weight prep: W0 [128][64] -> W0t bf16 [64][128]; W1 [64][32] -> W1t bf16 [32][64]
__global__ __launch_bounds__(256) void prep_w_kernel(
    const float* __restrict__ W0, const float* __restrict__ W1,
    unsigned short* __restrict__ W0t, unsigned short* __restrict__ W1t) {
    int t = blockIdx.x * 256 + threadIdx.x;
    int stride = gridDim.x * 256;
    for (int o = t; o < 64 * 128; o += stride) {
        int n = o >> 7, k = o & 127;
        W0t[o] = f2bf(W0[k * 64 + n]);
    }
    for (int o = t; o < 32 * 64; o += stride) {
        int n = o >> 6, k = o & 63;
        W1t[o] = f2bf(W1[k * 32 + n]);
    }
}

// ---------------------------------------------------------------- pass 1a: per-chunk histogram + reservation
__global__ __launch_bounds__(256) void hist_kernel(
    const int* __restrict__ dst, int* __restrict__ gcursor,
    int* __restrict__ blockres, int E, int nbucket) {
    __shared__ int hist[MAXB];
    const int tid = threadIdx.x;
    const int e0 = blockIdx.x * CHUNK;
    const int e1 = min(e0 + CHUNK, E);
    for (int b = tid; b < nbucket; b += 256) hist[b] = 0;
    __syncthreads();
    for (int e = e0 + tid; e < e1; e += 256)
        atomicAdd(&hist[dst[e] >> NPB_SH], 1);
    __syncthreads();
    int* res = blockres + (size_t)blockIdx.x * nbucket;
    for (int b = tid; b < nbucket; b += 256)
        res[b] = atomicAdd(&gcursor[b], hist[b]);
}

// exclusive scan of bucket counts (nb <= 512), bbase[nb] = total
__global__ __launch_bounds__(512) void bucket_scan_kernel(const int* __restrict__ gcursor,
                                                          int* __restrict__ bbase, int nb) {
    __shared__ int tmp[512];
    int i = threadIdx.x;
    int v = (i < nb) ? gcursor[i] : 0;
    tmp[i] = v;
    __syncthreads();
    for (int o = 1; o < 512; o <<= 1) {
        int t = (i >= o) ? tmp[i - o] : 0;
        __syncthreads();
        tmp[i] += t;
        __syncthreads();
    }
    if (i < nb) bbase[i] = tmp[i] - v;
    if (i == nb - 1) bbase[nb] = tmp[i];
}

// ---------------------------------------------------------------- pass 1b: place edges into bucket segments
// tmp entry: {src | (dst&255)<<17, bits(w)}  (src < 2^17)
__global__ __launch_bounds__(256) void scatter_bucket_kernel(
    const int* __restrict__ src, const int* __restrict__ dst,
    const float* __restrict__ ew, const int* __restrict__ bbase,
    const int* __restrict__ blockres, int2* __restrict__ tmp,
    int E, int nbucket) {
    __shared__ int base[MAXB];
    __shared__ int cur[MAXB];
    const int tid = threadIdx.x;
    const int e0 = blockIdx.x * CHUNK;
    const int e1 = min(e0 + CHUNK, E);
    const int* res = blockres + (size_t)blockIdx.x * nbucket;
    for (int b = tid; b < nbucket; b += 256) {
        base[b] = bbase[b] + res[b];
        cur[b] = 0;
    }
    __syncthreads();
    for (int e = e0 + tid; e < e1; e += 256) {
        int d = dst[e];
        int b = d >> NPB_SH;
        int r = atomicAdd(&cur[b], 1);
        tmp[base[b] + r] =
            make_int2(src[e] | ((d & (NPB - 1)) << 17), __float_as_int(ew[e]));
    }
}

// ---------------------------------------------------------------- pass 2: per-bucket CSR + rowptr + dinv
__global__ __launch_bounds__(256) void csr_kernel(
    const int2* __restrict__ tmp, const int* __restrict__ bbase,
    int2* __restrict__ es, int* __restrict__ rowptr, float* __restrict__ dinv,
    int N, int E) {
    __shared__ int cnt[256];
    __shared__ float dw[256];
    __shared__ int off[256];
    __shared__ int cur[256];
    const int t = threadIdx.x;
    const int n0 = blockIdx.x << NPB_SH;
    cnt[t] = 0;
    dw[t] = 0.f;
    __syncthreads();
    const int bb = bbase[blockIdx.x], be = bbase[blockIdx.x + 1];
    for (int p = bb + t; p < be; p += 256) {
        int2 e = tmp[p];
        int d = e.x >> 17;
        atomicAdd(&cnt[d], 1);
        atomicAdd(&dw[d], __int_as_float(e.y));
    }
    __syncthreads();
    int v = cnt[t];
    off[t] = v;
    __syncthreads();
    for (int o = 1; o < 256; o <<= 1) {
        int x = (t >= o) ? off[t - o] : 0;
        __syncthreads();
        off[t] += x;
        __syncthreads();
    }
    int excl = off[t] - v;
    cur[t] = excl;
    int n = n0 + t;
    if (n < N) {
        rowptr[n] = bb + excl;
        dinv[n] = rsqrtf(fmaxf(1.f + dw[t], 1e-12f));
    }
    if (blockIdx.x == 0 && t == 0) rowptr[N] = E;
    __syncthreads();
    for (int p = bb + t; p < be; p += 256) {
        int2 e = tmp[p];
        int d = e.x >> 17;
        int r = atomicAdd(&cur[d], 1);
        es[bb + r] = make_int2(e.x & 0x1FFFF, e.y);
    }
}

// ---------------------------------------------------------------- gemm1 (MFMA): M = bf16(dinv * (X f32 @ W0)), K=128, NOUT=64
// block = 256 (4 waves x 16 rows); A-frag loaded from global (fp32->bf16 in reg),
// B-frag from LDS-staged W0t rows (16B contiguous per lane).
__global__ __launch_bounds__(256) void gemm1_mfma_kernel(
    const float* __restrict__ X, const unsigned short* __restrict__ W0t,
    const float* __restrict__ dinv, unsigned short* __restrict__ M, int N) {
    __shared__ unsigned short Bs[64][136];   // +8 pad: lane stride 68 dw -> 2-way banks (free)
    const int tid = threadIdx.x;
    for (int i = tid; i < 64 * 32; i += 256) {           // 2048 ushort4
        int n = i >> 5, k4 = i & 31;
        ushort4 v = ((const ushort4*)W0t)[i];
        *(ushort4*)&Bs[n][k4 * 4] = v;
    }
    __syncthreads();
    const int wave = tid >> 6, lane = tid & 63;
    const int m = lane & 15, q = lane >> 4;
    const int rowA = blockIdx.x * 64 + wave * 16 + m;
    const bool rok = rowA < N;
    const float* xrow = X + (size_t)rowA * 128;
    f32x4 acc[4] = {};
#pragma unroll
    for (int ks = 0; ks < 4; ++ks) {
        int k0 = ks * 32 + q * 8;
        float4 u0 = make_float4(0.f, 0.f, 0.f, 0.f);
        float4 u1 = make_float4(0.f, 0.f, 0.f, 0.f);
        if (rok) {
            u0 = *(const float4*)(xrow + k0);
            u1 = *(const float4*)(xrow + k0 + 4);
        }
        short8 a;
        a[0] = (short)f2bf(u0.x); a[1] = (short)f2bf(u0.y);
        a[2] = (short)f2bf(u0.z); a[3] = (short)f2bf(u0.w);
        a[4] = (short)f2bf(u1.x); a[5] = (short)f2bf(u1.y);
        a[6] = (short)f2bf(u1.z); a[7] = (short)f2bf(u1.w);
#pragma unroll
        for (int ct = 0; ct < 4; ++ct) {
            short8 b = *(const short8*)&Bs[ct * 16 + m][k0];
            acc[ct] = __builtin_amdgcn_mfma_f32_16x16x32_bf16(a, b, acc[ct], 0, 0, 0);
        }
    }
    // C/D: col = ct*16 + (lane&15), row = (lane>>4)*4 + reg
#pragma unroll
    for (int r = 0; r < 4; ++r) {
        int crow = blockIdx.x * 64 + wave * 16 + q * 4 + r;
        if (crow < N) {
            float d = dinv[crow];
#pragma unroll
            for (int ct = 0; ct < 4; ++ct)
                M[(size_t)crow * 64 + ct * 16 + m] = f2bf(acc[ct][r] * d);
        }
    }
}

// ---------------------------------------------------------------- gemm2 (MFMA): m1p = bf16(dinv * (H1 bf16 @ W1)), K=64, NOUT=32
__global__ __launch_bounds__(256) void gemm2_mfma_kernel(
    const unsigned short* __restrict__ H1, const unsigned short* __restrict__ W1t,
    const float* __restrict__ dinv, unsigned short* __restrict__ M, int N) {
    __shared__ unsigned short Bs[32][72];
    const int tid = threadIdx.x;
    for (int i = tid; i < 32 * 16; i += 256) {           // 512 ushort4
        int n = i >> 4, k4 = i & 15;
        ushort4 v = ((const ushort4*)W1t)[i];
        *(ushort4*)&Bs[n][k4 * 4] = v;
    }
    __syncthreads();
    const int wave = tid >> 6, lane = tid & 63;
    const int m = lane & 15, q = lane >> 4;
    const int rowA = blockIdx.x * 64 + wave * 16 + m;
    const bool rok = rowA < N;
    const short8 az = {0, 0, 0, 0, 0, 0, 0, 0};
    f32x4 acc[2] = {};
#pragma unroll
    for (int ks = 0; ks < 2; ++ks) {
        int k0 = ks * 32 + q * 8;
        short8 a = rok ? *(const short8*)(H1 + (size_t)rowA * 64 + k0) : az;
#pragma unroll
        for (int ct = 0; ct < 2; ++ct) {
            short8 b = *(const short8*)&Bs[ct * 16 + m][k0];
            acc[ct] = __builtin_amdgcn_mfma_f32_16x16x32_bf16(a, b, acc[ct], 0, 0, 0);
        }
    }
#pragma unroll
    for (int r = 0; r < 4; ++r) {
        int crow = blockIdx.x * 64 + wave * 16 + q * 4 + r;
        if (crow < N) {
            float d = dinv[crow];
#pragma unroll
            for (int ct = 0; ct < 2; ++ct)
                M[(size_t)crow * 32 + ct * 16 + m] = f2bf(acc[ct][r] * d);
        }
    }
}

// ---------------------------------------------------------------- pull1: wave per node, 4-edge ILP
// H1[node] = bf16( relu( dinv*(m'[node] + sum w*m'[src]) + b0 ) )
__global__ __launch_bounds__(256) void pull1_kernel(
    const int* __restrict__ rowptr, const int2* __restrict__ es,
    const unsigned short* __restrict__ M, const float* __restrict__ dinv,
    const float* __restrict__ bias, unsigned short* __restrict__ H1, int N) {
    const int lane = threadIdx.x & 63;
    const int node = blockIdx.x * 4 + (threadIdx.x >> 6);
    if (node >= N) return;                 // whole wave exits; no barriers below
    const int c = lane & 15, q = lane >> 4;
    float4 acc = make_float4(0.f, 0.f, 0.f, 0.f);
    if (q == 0) {                           // self-loop counted once
        ushort4 su = *(const ushort4*)(M + (size_t)node * 64 + c * 4);
        acc = make_float4(bf2f(su.x), bf2f(su.y), bf2f(su.z), bf2f(su.w));
    }
    const int b = rowptr[node], e = rowptr[node + 1];
    for (int p = b + q; p < e; p += 4) {    // 4 independent gather chains
        int2 ed = es[p];
        float w = __int_as_float(ed.y);
        ushort4 u = *(const ushort4*)(M + (size_t)ed.x * 64 + c * 4);
        acc.x = fmaf(w, bf2f(u.x), acc.x);
        acc.y = fmaf(w, bf2f(u.y), acc.y);
        acc.z = fmaf(w, bf2f(u.z), acc.z);
        acc.w = fmaf(w, bf2f(u.w), acc.w);
    }
#pragma unroll
    for (int off = 16; off < 64; off <<= 1) {
        acc.x += __shfl_xor(acc.x, off);
        acc.y += __shfl_xor(acc.y, off);
        acc.z += __shfl_xor(acc.z, off);
        acc.w += __shfl_xor(acc.w, off);
    }
    if (q == 0) {
        float d = dinv[node];
        float4 bb = *(const float4*)(bias + c * 4);
        ushort4 o;
        o.x = f2bf(fmaxf(fmaf(d, acc.x, bb.x), 0.f));
        o.y = f2bf(fmaxf(fmaf(d, acc.y, bb.y), 0.f));
        o.z = f2bf(fmaxf(fmaf(d, acc.z, bb.z), 0.f));
        o.w = f2bf(fmaxf(fmaf(d, acc.w, bb.w), 0.f));
        *(ushort4*)(H1 + (size_t)node * 64 + c * 4) = o;
    }
}

// ---------------------------------------------------------------- pull2 + fused sum-pool: wave per node, 8-edge ILP
__global__ __launch_bounds__(256) void pull2_pool_kernel(
    const int* __restrict__ rowptr, const int2* __restrict__ es,
    const unsigned short* __restrict__ M, const float* __restrict__ dinv,
    const float* __restrict__ bias, const int* __restrict__ ngi,
    float* __restrict__ g, int N) {
    __shared__ float4 sh[4][8];
    __shared__ int sgx[4];
    const int lane = threadIdx.x & 63;
    const int w = threadIdx.x >> 6;
    const int node = blockIdx.x * 4 + w;
    const int c = lane & 7, q = lane >> 3;
    const bool valid = node < N;
    float4 acc = make_float4(0.f, 0.f, 0.f, 0.f);
    if (valid) {
        if (q == 0) {
            ushort4 su = *(const ushort4*)(M + (size_t)node * 32 + c * 4);
            acc = make_float4(bf2f(su.x), bf2f(su.y), bf2f(su.z), bf2f(su.w));
        }
        const int b = rowptr[node], e = rowptr[node + 1];
        for (int p = b + q; p < e; p += 8) {   // 8 independent gather chains
            int2 ed = es[p];
            float ww = __int_as_float(ed.y);
            ushort4 u = *(const ushort4*)(M + (size_t)ed.x * 32 + c * 4);
            acc.x = fmaf(ww, bf2f(u.x), acc.x);
            acc.y = fmaf(ww, bf2f(u.y), acc.y);
            acc.z = fmaf(ww, bf2f(u.z), acc.z);
            acc.w = fmaf(ww, bf2f(u.w), acc.w);
        }
#pragma unroll
        for (int off = 8; off < 64; off <<= 1) {
            acc.x += __shfl_xor(acc.x, off);
            acc.y += __shfl_xor(acc.y, off);
            acc.z += __shfl_xor(acc.z, off);
            acc.w += __shfl_xor(acc.w, off);
        }
    }
    if (q == 0) {                          // lanes 0..7 of each wave
        float4 o = make_float4(0.f, 0.f, 0.f, 0.f);
        if (valid) {
            float d = dinv[node];
            float4 bb = *(const float4*)(bias + c * 4);
            o.x = fmaxf(fmaf(d, acc.x, bb.x), 0.f);
            o.y = fmaxf(fmaf(d, acc.y, bb.y), 0.f);
            o.z = fmaxf(fmaf(d, acc.z, bb.z), 0.f);
            o.w = fmaxf(fmaf(d, acc.w, bb.w), 0.f);
        }
        sh[w][c] = o;
        if (c == 0) sgx[w] = valid ? ngi[node] : -1;
    }
    __syncthreads();
    if (threadIdx.x < 8) {                 // run-length combine across the block's 4 nodes
        int cc = threadIdx.x;
        float4 a = make_float4(0.f, 0.f, 0.f, 0.f);
        int cg = -1;
        for (int i = 0; i < 4; ++i) {
            int gi = sgx[i];
            if (gi < 0) continue;
            if (gi != cg) {
                if (cg >= 0) {
                    float* gp = g + cg * 32 + cc * 4;
                    atomicAdd(gp + 0, a.x); atomicAdd(gp + 1, a.y);
                    atomicAdd(gp + 2, a.z); atomicAdd(gp + 3, a.w);
                }
                cg = gi;
                a = sh[i][cc];
            } else {
                float4 t = sh[i][cc];
                a.x += t.x; a.y += t.y; a.z += t.z; a.w += t.w;
            }
        }
        if (cg >= 0) {
            float* gp = g + cg * 32 + cc * 4;
            atomicAdd(gp + 0, a.x); atomicAdd(gp + 1, a.y);
            atomicAdd(gp + 2, a.z); atomicAdd(gp + 3, a.w);
        }
    }
}

// ---------------------------------------------------------------- MLP head
__global__ __launch_bounds__(128) void mlp_kernel(
    const float* __restrict__ g, const float* __restrict__ Wm1,
    const float* __restrict__ bm1, const float* __restrict__ Wm2,
    const float* __restrict__ bm2, float* __restrict__ out) {
    __shared__ float sg[32];
    __shared__ float st[128];
    int b = blockIdx.x, t = threadIdx.x;
    if (t < 32) sg[t] = g[b * 32 + t];
    __syncthreads();
    float acc = bm1[t];
#pragma unroll
    for (int k = 0; k < 32; ++k) acc = fmaf(sg[k], Wm1[k * 128 + t], acc);
    st[t] = fmaxf(acc, 0.f);
    __syncthreads();
    if (t < 2) {
        float o = bm2[t];
#pragma unroll
        for (int k = 0; k < 128; ++k) o = fmaf(st[k], Wm2[k * 2 + t], o);
        out[b * 2 + t] = o;
    }
}

// ---------------------------------------------------------------- launch

extern "C" void kernel_launch(void* const* d_in, const int* in_sizes, int n_in,
                              void* d_out, int out_size, void* d_ws, size_t ws_size,
                              hipStream_t stream) {
    const float* x   = (const float*)d_in[0];
    const int*   ei  = (const int*)d_in[1];
    const float* ew  = (const float*)d_in[2];
    const int*   ngi = (const int*)d_in[3];
    const float* W0  = (const float*)d_in[4];
    const float* b0  = (const float*)d_in[5];
    const float* W1  = (const float*)d_in[6];
    const float* b1  = (const float*)d_in[7];
    const float* Wm1 = (const float*)d_in[8];
    const float* bm1 = (const float*)d_in[9];
    const float* Wm2 = (const float*)d_in[10];
    const float* bm2 = (const float*)d_in[11];
    float* out = (float*)d_out;

    const int N = in_sizes[0] / F_IN;       // 100000 (< 2^17, packing requirement)
    const int E = in_sizes[1] / 2;          // 1600000
    const int G = out_size / 2;             // 1000
    const int* srcp = ei;
    const int* dstp = ei + E;
    const int NBUCKET = (N + NPB - 1) >> NPB_SH;       // 391
    const int NBLK = (E + CHUNK - 1) / CHUNK;          // 196

    // workspace layout (256B-aligned chunks)
    char* wsb = (char*)d_ws;
    size_t off = 0;
    auto alloc = [&](size_t bytes) {
        char* p = wsb + off;
        off += (bytes + 255) & ~(size_t)255;
        return p;
    };
    float* dinv     = (float*)alloc((size_t)N * 4);
    int*   gcursor  = (int*)  alloc((size_t)NBUCKET * 4);
    int*   bbase    = (int*)  alloc((size_t)(NBUCKET + 1) * 4);
    int*   rowptr   = (int*)  alloc((size_t)(N + 1) * 4);
    int*   blockres = (int*)  alloc((size_t)NBLK * NBUCKET * 4);
    int2*  es       = (int2*) alloc((size_t)E * 8);
    unsigned short* W0t = (unsigned short*)alloc(64 * 128 * 2);
    unsigned short* W1t = (unsigned short*)alloc(32 * 64 * 2);
    unsigned short* M   = (unsigned short*)alloc((size_t)N * 64 * 2);  // m0' bf16; m1' aliases low half later
    unsigned short* H1  = (unsigned short*)alloc((size_t)N * 64 * 2);  // h1 bf16 (tmp aliases, dead before pull1)
    float* Gbuf     = (float*)alloc((size_t)G * 32 * 4);
    int2* tmp = (int2*)H1;              // bucketed edges: E*8 == N*64*2 bytes
    unsigned short* m1p = M;            // N*32 bf16 (m0' dead after pull1)

    // 1. weight prep + CSR build
    hipMemsetAsync(gcursor, 0, (size_t)NBUCKET * 4, stream);
    prep_w_kernel<<<8, 256, 0, stream>>>(W0, W1, W0t, W1t);
    hist_kernel<<<NBLK, 256, 0, stream>>>(dstp, gcursor, blockres, E, NBUCKET);
    bucket_scan_kernel<<<1, 512, 0, stream>>>(gcursor, bbase, NBUCKET);
    scatter_bucket_kernel<<<NBLK, 256, 0, stream>>>(srcp, dstp, ew, bbase, blockres, tmp, E, NBUCKET);
    csr_kernel<<<NBUCKET, 256, 0, stream>>>(tmp, bbase, es, rowptr, dinv, N, E);

    // 2. layer 1: m0' = bf16(dinv*(x@W0)) via MFMA; pull (wave/node) -> h1 bf16
    gemm1_mfma_kernel<<<(N + 63) / 64, 256, 0, stream>>>(x, W0t, dinv, M, N);
    pull1_kernel<<<(N + 3) / 4, 256, 0, stream>>>(rowptr, es, M, dinv, b0, H1, N);

    // 3. layer 2: m1' = bf16(dinv*(h1@W1)) via MFMA; pull + fused sum-pool
    gemm2_mfma_kernel<<<(N + 63) / 64, 256, 0, stream>>>(H1, W1t, dinv, m1p, N);
    hipMemsetAsync(Gbuf, 0, (size_t)G * 32 * 4, stream);
    pull2_pool_kernel<<<(N + 3) / 4, 256, 0, stream>>>(rowptr, es, m1p, dinv, b1, ngi, Gbuf, N);

    // 4. MLP head
    mlp_kernel<<<G, 128, 0, stream>>>(Gbuf, Wm1, bm1, Wm2, bm2, out);
}